// Round 2
// baseline (189.830 us; speedup 1.0000x reference)
//
#include <hip/hip_runtime.h>
#include <math.h>

#define NN 256
#define TT 256
#define DD 1024
#define HH 1024

// ---------------------------------------------------------------------------
// Kernel 1a: partial max-pool over token dim. grid (256, 2, 4), block 256.
// Each block: one (n, tensor, t-chunk of 64 tokens). 2048 blocks -> 8/CU,
// full occupancy to saturate HBM. Thread d4 owns a float4 column.
// ---------------------------------------------------------------------------
__global__ __launch_bounds__(256) void pool_partial(const float* __restrict__ subs,
                                                    const float* __restrict__ objs,
                                                    float* __restrict__ partial) {
    const int n = blockIdx.x;
    const int which = blockIdx.y;
    const int tc = blockIdx.z;
    const float* src = (which == 0) ? subs : objs;
    const int d4 = threadIdx.x;
    const float4* base = reinterpret_cast<const float4*>(src + (size_t)n * TT * DD) +
                         (size_t)tc * 64 * (DD / 4) + d4;

    float4 a0 = make_float4(-INFINITY, -INFINITY, -INFINITY, -INFINITY);
    float4 a1 = a0, a2 = a0, a3 = a0;
    for (int t = 0; t < 64; t += 4) {
        float4 v0 = base[(size_t)(t + 0) * (DD / 4)];
        float4 v1 = base[(size_t)(t + 1) * (DD / 4)];
        float4 v2 = base[(size_t)(t + 2) * (DD / 4)];
        float4 v3 = base[(size_t)(t + 3) * (DD / 4)];
        a0.x = fmaxf(a0.x, v0.x); a0.y = fmaxf(a0.y, v0.y); a0.z = fmaxf(a0.z, v0.z); a0.w = fmaxf(a0.w, v0.w);
        a1.x = fmaxf(a1.x, v1.x); a1.y = fmaxf(a1.y, v1.y); a1.z = fmaxf(a1.z, v1.z); a1.w = fmaxf(a1.w, v1.w);
        a2.x = fmaxf(a2.x, v2.x); a2.y = fmaxf(a2.y, v2.y); a2.z = fmaxf(a2.z, v2.z); a2.w = fmaxf(a2.w, v2.w);
        a3.x = fmaxf(a3.x, v3.x); a3.y = fmaxf(a3.y, v3.y); a3.z = fmaxf(a3.z, v3.z); a3.w = fmaxf(a3.w, v3.w);
    }
    float4 m;
    m.x = fmaxf(fmaxf(a0.x, a1.x), fmaxf(a2.x, a3.x));
    m.y = fmaxf(fmaxf(a0.y, a1.y), fmaxf(a2.y, a3.y));
    m.z = fmaxf(fmaxf(a0.z, a1.z), fmaxf(a2.z, a3.z));
    m.w = fmaxf(fmaxf(a0.w, a1.w), fmaxf(a2.w, a3.w));
    // layout: partial[tc][which][n][d]
    float4* dst = reinterpret_cast<float4*>(partial + ((size_t)(tc * 2 + which) * NN + n) * DD) + d4;
    *dst = m;
}

// Kernel 1b: reduce the 4 partials. grid 512, block 256.
__global__ __launch_bounds__(256) void pool_reduce(const float* __restrict__ partial,
                                                   float* __restrict__ pooled) {
    const int row = blockIdx.x;          // which*NN + n, 0..511
    const int d4 = threadIdx.x;
    const float4* p = reinterpret_cast<const float4*>(partial) + (size_t)row * (DD / 4) + d4;
    const size_t stride = (size_t)2 * NN * (DD / 4);  // one tc step
    float4 v0 = p[0];
    float4 v1 = p[stride];
    float4 v2 = p[2 * stride];
    float4 v3 = p[3 * stride];
    float4 m;
    m.x = fmaxf(fmaxf(v0.x, v1.x), fmaxf(v2.x, v3.x));
    m.y = fmaxf(fmaxf(v0.y, v1.y), fmaxf(v2.y, v3.y));
    m.z = fmaxf(fmaxf(v0.z, v1.z), fmaxf(v2.z, v3.z));
    m.w = fmaxf(fmaxf(v0.w, v1.w), fmaxf(v2.w, v3.w));
    reinterpret_cast<float4*>(pooled)[(size_t)row * (DD / 4) + d4] = m;
}

// ---------------------------------------------------------------------------
// Kernel 2: fp32 GEMM  out[m][h] = sum_d A[m][d] * W1[h][koff+d]  (+b1 if sub)
// BM=64, BN=32, BK=32; 256 threads; micro-tile 4(m) x 2(n); grid (32,8)=256.
// Fragments read as k-quads: A stored m-outer [64][36], B n-outer [32][36]
// (pad 36 keeps b128 16B-alignment and spreads banks). 6 ds_read_b128 per
// 32 FMA per wave -> FMA-bound, not LDS-issue-bound. Register prefetch of
// the next K-chunk hides global latency (1 block/CU).
// ---------------------------------------------------------------------------
#define BM 64
#define BN 32
#define BK 32
#define LDP 36

__global__ __launch_bounds__(256) void gemm_kernel(const float* __restrict__ A,
                                                   const float* __restrict__ W1,
                                                   const float* __restrict__ b1,
                                                   float* __restrict__ out) {
    __shared__ float As[BM][LDP];
    __shared__ float Bs[BN][LDP];
    const int t = threadIdx.x;
    const int nx = t & 15;       // n pair index: cols nx*2, nx*2+1
    const int tm = t >> 4;       // m quad index: rows tm*4 .. tm*4+3
    const int m0 = blockIdx.y * BM;
    const int n0 = blockIdx.x * BN;
    const bool is_sub = (m0 < NN);
    const int koff = is_sub ? 0 : DD;

    // staging geometry
    const int a_row = t >> 3;        // 0..31 (+32 second pass)
    const int a_k = (t & 7) * 4;
    const int b_row = t >> 3;        // 0..31
    const int b_k = (t & 7) * 4;

    const float* Aptr0 = A + (size_t)(m0 + a_row) * DD + a_k;
    const float* Aptr1 = A + (size_t)(m0 + a_row + 32) * DD + a_k;
    const float* Bptr = W1 + (size_t)(n0 + b_row) * (2 * DD) + koff + b_k;

    float acc[4][2];
#pragma unroll
    for (int i = 0; i < 4; ++i) { acc[i][0] = 0.f; acc[i][1] = 0.f; }

    // prologue: chunk 0
    float4 pa0 = *(const float4*)(Aptr0);
    float4 pa1 = *(const float4*)(Aptr1);
    float4 pb  = *(const float4*)(Bptr);
    *(float4*)&As[a_row][a_k] = pa0;
    *(float4*)&As[a_row + 32][a_k] = pa1;
    *(float4*)&Bs[b_row][b_k] = pb;
    __syncthreads();

    const int NCHUNK = DD / BK;  // 32
    for (int c = 0; c < NCHUNK; ++c) {
        float4 na0, na1, nb;
        if (c + 1 < NCHUNK) {
            const int off = (c + 1) * BK;
            na0 = *(const float4*)(Aptr0 + off);
            na1 = *(const float4*)(Aptr1 + off);
            nb  = *(const float4*)(Bptr + off);
        }
#pragma unroll
        for (int kq = 0; kq < BK; kq += 4) {
            float4 a[4], b[2];
#pragma unroll
            for (int i = 0; i < 4; ++i) a[i] = *(const float4*)&As[tm * 4 + i][kq];
#pragma unroll
            for (int j = 0; j < 2; ++j) b[j] = *(const float4*)&Bs[nx * 2 + j][kq];
#pragma unroll
            for (int i = 0; i < 4; ++i) {
#pragma unroll
                for (int j = 0; j < 2; ++j) {
                    acc[i][j] += a[i].x * b[j].x;
                    acc[i][j] += a[i].y * b[j].y;
                    acc[i][j] += a[i].z * b[j].z;
                    acc[i][j] += a[i].w * b[j].w;
                }
            }
        }
        __syncthreads();
        if (c + 1 < NCHUNK) {
            *(float4*)&As[a_row][a_k] = na0;
            *(float4*)&As[a_row + 32][a_k] = na1;
            *(float4*)&Bs[b_row][b_k] = nb;
            __syncthreads();
        }
    }

    // epilogue: fold b1 into subject half
    float2 bias = make_float2(0.f, 0.f);
    if (is_sub) bias = *(const float2*)&b1[n0 + nx * 2];
#pragma unroll
    for (int i = 0; i < 4; ++i) {
        const int mg = m0 + tm * 4 + i;
        float2 r;
        r.x = acc[i][0] + bias.x;
        r.y = acc[i][1] + bias.y;
        *(float2*)&out[(size_t)mg * HH + n0 + nx * 2] = r;
    }
}

// ---------------------------------------------------------------------------
// Kernel 3: pair scores.  scores[i,j] = sum_h relu(sp[i,h]+op[j,h]) * w2[h] + b2
// grid (16,16), 256 threads, 1 pair/thread. sp/op tiles staged in LDS via
// register prefetch (global latency hidden under compute). W2 read with a
// block-uniform index -> scalar loads, no LDS.
// ---------------------------------------------------------------------------
#define HC 128

__global__ __launch_bounds__(256) void pair_kernel(const float* __restrict__ sp_op,
                                                   const float* __restrict__ W2,
                                                   const float* __restrict__ b2,
                                                   float* __restrict__ out) {
    __shared__ float sT[16][HC + 4];
    __shared__ float oT[16][HC + 4];
    const int t = threadIdx.x;
    const int tx = t & 15, ty = t >> 4;
    const int i0 = blockIdx.y * 16, j0 = blockIdx.x * 16;
    const float* sp = sp_op;                       // rows 0..255 (b1 folded)
    const float* op = sp_op + (size_t)NN * HH;     // rows 256..511

    const int s_row = t >> 5;        // 0..1 per wave pattern; +8 in round 1
    const int s_h = (t & 31) * 4;    // 0..124

    // prefetch chunk 0 into registers
    float4 rs[2], ro[2];
#pragma unroll
    for (int r = 0; r < 2; ++r) {
        const int row = s_row + r * 8;
        rs[r] = *(const float4*)&sp[(size_t)(i0 + row) * HH + s_h];
        ro[r] = *(const float4*)&op[(size_t)(j0 + row) * HH + s_h];
    }

    float acc = 0.f;
    for (int c = 0; c < HH / HC; ++c) {
#pragma unroll
        for (int r = 0; r < 2; ++r) {
            const int row = s_row + r * 8;
            *(float4*)&sT[row][s_h] = rs[r];
            *(float4*)&oT[row][s_h] = ro[r];
        }
        float4 ns[2], no[2];
        if (c + 1 < HH / HC) {
#pragma unroll
            for (int r = 0; r < 2; ++r) {
                const int row = s_row + r * 8;
                ns[r] = *(const float4*)&sp[(size_t)(i0 + row) * HH + (c + 1) * HC + s_h];
                no[r] = *(const float4*)&op[(size_t)(j0 + row) * HH + (c + 1) * HC + s_h];
            }
        }
        __syncthreads();
#pragma unroll
        for (int h4 = 0; h4 < HC / 4; ++h4) {
            float4 s = *(const float4*)&sT[ty][h4 * 4];
            float4 o = *(const float4*)&oT[tx][h4 * 4];
            float4 w = *(const float4*)&W2[c * HC + h4 * 4];  // block-uniform -> s_load
            acc += fmaxf(s.x + o.x, 0.f) * w.x;
            acc += fmaxf(s.y + o.y, 0.f) * w.y;
            acc += fmaxf(s.z + o.z, 0.f) * w.z;
            acc += fmaxf(s.w + o.w, 0.f) * w.w;
        }
        __syncthreads();
#pragma unroll
        for (int r = 0; r < 2; ++r) { rs[r] = ns[r]; ro[r] = no[r]; }
    }
    const int i = i0 + ty, j = j0 + tx;
    const float score = acc + b2[0];
    out[i * NN + j] = (i == j) ? 0.f : score;
}

// ---------------------------------------------------------------------------
extern "C" void kernel_launch(void* const* d_in, const int* in_sizes, int n_in,
                              void* d_out, int out_size, void* d_ws, size_t ws_size,
                              hipStream_t stream) {
    const float* subs = (const float*)d_in[0];
    const float* objs = (const float*)d_in[1];
    const float* W1   = (const float*)d_in[2];
    const float* b1   = (const float*)d_in[3];
    const float* W2   = (const float*)d_in[4];
    const float* b2   = (const float*)d_in[5];
    float* out = (float*)d_out;

    float* partial = (float*)d_ws;                       // [4][2][256][1024] = 8 MB
    float* pooled  = partial + (size_t)8 * NN * DD;      // [512][1024] = 2 MB
    float* sp_op   = pooled + (size_t)2 * NN * DD;       // [512][1024] = 2 MB

    pool_partial<<<dim3(NN, 2, 4), 256, 0, stream>>>(subs, objs, partial);
    pool_reduce<<<dim3(2 * NN), 256, 0, stream>>>(partial, pooled);
    gemm_kernel<<<dim3(HH / BN, (2 * NN) / BM), 256, 0, stream>>>(pooled, W1, b1, sp_op);
    pair_kernel<<<dim3(NN / 16, NN / 16), 256, 0, stream>>>(sp_op, W2, b2, out);
}